// Round 1
// baseline (719.631 us; speedup 1.0000x reference)
//
#include <hip/hip_runtime.h>
#include <cstdint>
#include <cstddef>

typedef short short8 __attribute__((ext_vector_type(8)));
typedef float f32x4 __attribute__((ext_vector_type(4)));

#define DIN  4096
#define DOUT 4096
#define RANK 64
#define NEXP 16
#define NTOK 8192
#define KCAT 5120   // DIN + NEXP*RANK
#define NKT  (KCAT / 64)   // 80 K-tiles of 64

// ---------- helpers ----------
__device__ __forceinline__ unsigned short f2bf(float f) {
    unsigned int u = __builtin_bit_cast(unsigned int, f);
    u = (u + 0x7FFFu + ((u >> 16) & 1u)) >> 16;   // RNE
    return (unsigned short)u;
}
__device__ __forceinline__ void async_cp16(const void* g, void* lds) {
    __builtin_amdgcn_global_load_lds(
        (const __attribute__((address_space(1))) void*)g,
        (__attribute__((address_space(3))) void*)lds, 16, 0, 0);
}

// ---------- kernel 1: all conversion + fp32 router logits ----------
__global__ void __launch_bounds__(256) prep_all_kernel(
        const float* __restrict__ x, const float* __restrict__ rw,
        const float* __restrict__ bw, const float* __restrict__ Bm,
        const float* __restrict__ Am,
        unsigned short* __restrict__ Xcat, unsigned short* __restrict__ Wcat,
        unsigned short* __restrict__ W1A, float* __restrict__ Lg) {
    __shared__ __align__(16) float xsl[8][532];
    __shared__ __align__(16) float red[8][16][16];
    const int tid = threadIdx.x;

    if (blockIdx.x < 1024) {
        const int t0 = blockIdx.x * 8;
        const int tt = tid >> 5, l32 = tid & 31;
        const int eg = tid >> 6, ts = (tid >> 4) & 3, cc = tid & 15;
        float part[2][4] = {};

        for (int w = 0; w < 8; ++w) {
            #pragma unroll
            for (int sub = 0; sub < 4; ++sub) {
                const int col = w * 512 + sub * 128 + l32 * 4;
                const float4 xv = *(const float4*)&x[(size_t)(t0 + tt) * DIN + col];
                unsigned short b0 = f2bf(xv.x), b1 = f2bf(xv.y),
                               b2 = f2bf(xv.z), b3 = f2bf(xv.w);
                uint2 pk = { (unsigned)b0 | ((unsigned)b1 << 16),
                             (unsigned)b2 | ((unsigned)b3 << 16) };
                *(uint2*)&Xcat[(size_t)(t0 + tt) * KCAT + col] = pk;
                *(float4*)&xsl[tt][sub * 128 + l32 * 4] = xv;
            }
            __syncthreads();
            #pragma unroll
            for (int j = 0; j < 8; ++j) {
                const int colb = w * 512 + (j * 16 + cc) * 4;
                const float4 r0 = *(const float4*)&rw[(size_t)(eg * 4 + 0) * DIN + colb];
                const float4 r1 = *(const float4*)&rw[(size_t)(eg * 4 + 1) * DIN + colb];
                const float4 r2 = *(const float4*)&rw[(size_t)(eg * 4 + 2) * DIN + colb];
                const float4 r3 = *(const float4*)&rw[(size_t)(eg * 4 + 3) * DIN + colb];
                #pragma unroll
                for (int t2 = 0; t2 < 2; ++t2) {
                    const int t = ts * 2 + t2;
                    const float4 xv = *(const float4*)&xsl[t][(j * 16 + cc) * 4];
                    part[t2][0] += xv.x * r0.x + xv.y * r0.y + xv.z * r0.z + xv.w * r0.w;
                    part[t2][1] += xv.x * r1.x + xv.y * r1.y + xv.z * r1.z + xv.w * r1.w;
                    part[t2][2] += xv.x * r2.x + xv.y * r2.y + xv.z * r2.z + xv.w * r2.w;
                    part[t2][3] += xv.x * r3.x + xv.y * r3.y + xv.z * r3.z + xv.w * r3.w;
                }
            }
            __syncthreads();
        }
        #pragma unroll
        for (int t2 = 0; t2 < 2; ++t2)
            #pragma unroll
            for (int e = 0; e < 4; ++e)
                red[ts * 2 + t2][eg * 4 + e][cc] = part[t2][e];
        __syncthreads();
        if (tid < 128) {
            const int t = tid >> 4, e = tid & 15;
            float s = 0.f;
            #pragma unroll
            for (int c = 0; c < 16; ++c) s += red[t][e][c];
            Lg[(size_t)(t0 + t) * NEXP + e] = s;
        }
    } else {
        const unsigned NG1 = (unsigned)DOUT * KCAT / 8u;       // 2,621,440
        const unsigned NGT = NG1 + 64u * DIN / 8u;             // + 32,768
        for (unsigned g = (blockIdx.x - 1024) * 256u + tid; g < NGT;
             g += 2048u * 256u) {
            const float* src;
            unsigned short* dst;
            if (g < NG1) {
                unsigned o  = g / 640u;
                unsigned c8 = (g - o * 640u) * 8u;
                dst = Wcat + (size_t)o * KCAT + c8;
                if (c8 < DIN) {
                    src = bw + (size_t)o * DIN + c8;
                } else {
                    unsigned cc2 = c8 - DIN;
                    unsigned e = cc2 >> 6, r = cc2 & 63u;
                    src = Bm + ((size_t)e * DOUT + o) * RANK + r;
                }
            } else {
                unsigned g2 = g - NG1;
                unsigned row = g2 >> 9;
                unsigned c8  = (g2 & 511u) * 8u;
                dst = W1A + (size_t)row * DIN + c8;
                src = Am + (size_t)row * DIN + c8;
            }
            float4 v0 = *(const float4*)(src);
            float4 v1 = *(const float4*)(src + 4);
            uint4 pk;
            pk.x = (unsigned)f2bf(v0.x) | ((unsigned)f2bf(v0.y) << 16);
            pk.y = (unsigned)f2bf(v0.z) | ((unsigned)f2bf(v0.w) << 16);
            pk.z = (unsigned)f2bf(v1.x) | ((unsigned)f2bf(v1.y) << 16);
            pk.w = (unsigned)f2bf(v1.z) | ((unsigned)f2bf(v1.w) << 16);
            *(uint4*)dst = pk;
        }
    }
}

// ---------- kernel 2: h = Xhi @ A^T (MFMA) + softmax/top2 -> H16 ----------
__global__ void __launch_bounds__(256) proj_moe_kernel(
        const unsigned short* __restrict__ Xcat,
        const unsigned short* __restrict__ W1A,
        const float* __restrict__ Lg, unsigned short* __restrict__ XcatW) {
    __shared__ __align__(16) unsigned short Xs[16 * 128];   // 4 KB
    __shared__ __align__(16) unsigned short Ws[64 * 128];   // 16 KB
    __shared__ __align__(16) float cw[16][16];
    __shared__ __align__(16) float hbuf[16][68];
    const int tid = threadIdx.x;
    const int wave = tid >> 6, lane = tid & 63;
    const int quad = lane >> 4, l16 = lane & 15;
    const int t0 = blockIdx.x * 16;

    const int rX = tid >> 4, cXs = tid & 15;
    const int cX = (cXs & 8) | ((cXs ^ rX) & 7);

    if (tid < 16) {
        float l[16];
        #pragma unroll
        for (int e = 0; e < 16; ++e) l[e] = Lg[(size_t)(t0 + tid) * NEXP + e];
        int i1 = 0; float b1v = l[0];
        #pragma unroll
        for (int e = 1; e < 16; ++e) if (l[e] > b1v) { b1v = l[e]; i1 = e; }
        int i2 = -1; float b2v = -1e30f;
        #pragma unroll
        for (int e = 0; e < 16; ++e) if (e != i1 && l[e] > b2v) { b2v = l[e]; i2 = e; }
        float S = 0.f;
        #pragma unroll
        for (int e = 0; e < 16; ++e) S += expf(l[e] - b1v);
        const float p1 = 1.0f / S;
        const float p2 = expf(b2v - b1v) / S;
        const float d = p1 + p2 + 1e-6f;
        const float c1 = 0.5f * p1 / d;
        const float c2 = 0.5f * p2 / d;
        #pragma unroll
        for (int e = 0; e < 16; ++e)
            cw[tid][e] = (e == i1) ? c1 : (e == i2) ? c2 : 0.0f;
    }

    f32x4 acc = {};
    for (int kt = 0; kt < DIN / 128; ++kt) {
        const int k0 = kt * 128;
        async_cp16(Xcat + (size_t)(t0 + rX) * KCAT + k0 + cX * 8,
                   (char*)Xs + wave * 1024);
        #pragma unroll
        for (int i = 0; i < 4; ++i) {
            const int s = i * 256 + tid;
            const int rW = s >> 4, cWs = s & 15;
            const int cWc = (cWs & 8) | ((cWs ^ rW) & 7);
            async_cp16(W1A + (size_t)rW * DIN + k0 + cWc * 8,
                       (char*)Ws + i * 4096 + wave * 1024);
        }
        __syncthreads();
        #pragma unroll
        for (int kk = 0; kk < 4; ++kk) {
            const int c = kk * 4 + quad;
            const int sa = ((c & 8) | ((c ^ l16) & 7)) << 3;
            const int rb = wave * 16 + l16;
            const int sb = ((c & 8) | ((c ^ rb) & 7)) << 3;
            short8 am = *(const short8*)&Xs[l16 * 128 + sa];
            short8 bn = *(const short8*)&Ws[rb * 128 + sb];
            acc = __builtin_amdgcn_mfma_f32_16x16x32_bf16(am, bn, acc, 0, 0, 0);
        }
        __syncthreads();
    }
    #pragma unroll
    for (int r = 0; r < 4; ++r)
        hbuf[quad * 4 + r][wave * 16 + l16] = acc[r];
    __syncthreads();
    const int t = tid >> 4, e = tid & 15;
    const float c = cw[t][e];
    unsigned short* dst = XcatW + (size_t)(t0 + t) * KCAT + DIN + e * 64;
    #pragma unroll
    for (int r8 = 0; r8 < 8; ++r8) {
        unsigned short o16[8];
        #pragma unroll
        for (int k = 0; k < 8; ++k)
            o16[k] = f2bf(c * hbuf[t][r8 * 8 + k]);
        uint4 pk;
        pk.x = (unsigned)o16[0] | ((unsigned)o16[1] << 16);
        pk.y = (unsigned)o16[2] | ((unsigned)o16[3] << 16);
        pk.z = (unsigned)o16[4] | ((unsigned)o16[5] << 16);
        pk.w = (unsigned)o16[6] | ((unsigned)o16[7] << 16);
        *(uint4*)(dst + r8 * 8) = pk;
    }
}

// ---------- kernel 3: out = Xcat @ Wcat^T + bias ----------
// 256x256 tile, BK=64, 8 waves (2M x 4N), 8-phase schedule with counted
// vmcnt(6) (T3+T4), chunk-XOR LDS swizzle (T2), setprio around MFMA (T5),
// XCD-aware block swizzle (T1). Raw s_barrier only - no vmcnt(0) in loop.
__global__ void __launch_bounds__(512, 2) gemm_main_kernel(
        const unsigned short* __restrict__ Xcat,
        const unsigned short* __restrict__ Wcat,
        const float* __restrict__ bias, float* __restrict__ out) {
    __shared__ __align__(16) unsigned short As[2][256 * 64];   // 2 x 32 KB
    __shared__ __align__(16) unsigned short Bs[2][256 * 64];   // 2 x 32 KB

    const int tid  = threadIdx.x;
    const int wave = tid >> 6, lane = tid & 63;
    const int l16  = lane & 15, quad = lane >> 4;
    const int wm   = wave >> 2, wn = wave & 3;

    // T1: XCD swizzle (512 blocks, 512 % 8 == 0 -> simple bijective remap)
    const int bid = blockIdx.x;
    const int swz = (bid & 7) * 64 + (bid >> 3);
    const int bm0 = (swz & 31) * 256;   // 32 M-tiles
    const int bn0 = (swz >> 5) * 256;   // 16 N-tiles

    // ---- staging source pointers (pre-swizzled global: LDS stays linear) ----
    // dest chunk (16B) c within a 1024-chunk unit: row = c>>3, slot = c&7;
    // content must be global k-chunk slot ^ (row&7)  (involution).
    const int urr = tid >> 3;                    // row within issue i=0
    const int cks = (tid & 7) ^ (urr & 7);       // pre-swizzled k-chunk
    const unsigned short* sA[2][2];
    const unsigned short* sB[2][2];
    #pragma unroll
    for (int h = 0; h < 2; ++h) {
        // A unit h rows: [wm-half0: bm0+h*64+0..63] then [wm-half1: +128]
        sA[h][0] = Xcat + (size_t)(bm0 +       h * 64 + urr) * KCAT + cks * 8;
        sA[h][1] = Xcat + (size_t)(bm0 + 128 + h * 64 + urr) * KCAT + cks * 8;
    }
    #pragma unroll
    for (int u = 0; u < 2; ++u) {
        sB[u][0] = Wcat + (size_t)(bn0 + u * 128 +      urr) * KCAT + cks * 8;
        sB[u][1] = Wcat + (size_t)(bn0 + u * 128 + 64 + urr) * KCAT + cks * 8;
    }

    auto stageA = [&](unsigned short* buf, int h, int tt) {
        async_cp16(sA[h][0] + (size_t)tt * 64,
                   (char*)(buf + (h * 1024 +       wave * 64) * 8));
        async_cp16(sA[h][1] + (size_t)tt * 64,
                   (char*)(buf + (h * 1024 + 512 + wave * 64) * 8));
    };
    auto stageB = [&](unsigned short* buf, int u, int tt) {
        async_cp16(sB[u][0] + (size_t)tt * 64,
                   (char*)(buf + (u * 1024 +       wave * 64) * 8));
        async_cp16(sB[u][1] + (size_t)tt * 64,
                   (char*)(buf + (u * 1024 + 512 + wave * 64) * 8));
    };

    // ---- LDS read offsets (swizzled slot = ck ^ (row&7), row&7 == l16&7) ----
    const int cko0 = ((quad)     ^ (l16 & 7)) * 8;   // kk = 0
    const int cko1 = ((4 + quad) ^ (l16 & 7)) * 8;   // kk = 1
    int arow[8], brow[4];
    #pragma unroll
    for (int m = 0; m < 8; ++m)
        arow[m] = ((m >> 2) * 128 + wm * 64 + (m & 3) * 16 + l16) * 64;
    #pragma unroll
    for (int n = 0; n < 4; ++n)
        brow[n] = (wn * 64 + n * 16 + l16) * 64;

    f32x4 acc[8][4] = {};
    short8 bf[4][2];

    // ---- prologue: T0 fully + T1 {B0,B1,Ah0}; 14 loads/wave, wait 8 ----
    stageB(Bs[0], 0, 0); stageB(Bs[0], 1, 0);
    stageA(As[0], 0, 0); stageA(As[0], 1, 0);
    stageB(Bs[1], 0, 1); stageB(Bs[1], 1, 1);
    stageA(As[1], 0, 1);
    asm volatile("s_waitcnt vmcnt(6)" ::: "memory");
    __builtin_amdgcn_s_barrier();

    for (int t = 0; t < NKT; ++t) {
        const int b = t & 1;
        const unsigned short* pA = As[b];
        const unsigned short* pB = Bs[b];
        unsigned short* Acur  = As[b];
        unsigned short* Anext = As[b ^ 1];
        unsigned short* Bcur  = Bs[b];
        const int ts1 = (t + 1 < NKT) ? t + 1 : t;   // clamped dummy at tail
        const int ts2 = (t + 2 < NKT) ? t + 2 : t;

        #pragma unroll
        for (int q = 0; q < 4; ++q) {
            short8 af[2][2];
            if (q == 0) {   // B front-loaded once per K-tile, held in regs
                #pragma unroll
                for (int n = 0; n < 4; ++n) {
                    bf[n][0] = *(const short8*)&pB[brow[n] + cko0];
                    bf[n][1] = *(const short8*)&pB[brow[n] + cko1];
                }
            }
            #pragma unroll
            for (int mm = 0; mm < 2; ++mm) {
                af[mm][0] = *(const short8*)&pA[arow[2 * q + mm] + cko0];
                af[mm][1] = *(const short8*)&pA[arow[2 * q + mm] + cko1];
            }
            // stage exactly 1 half-tile per phase; every victim region's
            // last read completed >=1 phase ago (drained by lgkm+barrier2)
            if      (q == 0) stageA(Anext, 1, ts1);
            else if (q == 1) stageB(Bcur, 0, ts2);
            else if (q == 2) stageB(Bcur, 1, ts2);
            else             stageA(Acur, 0, ts2);

            asm volatile("" ::: "memory");
            __builtin_amdgcn_s_barrier();
            asm volatile("s_waitcnt lgkmcnt(0)" ::: "memory");
            __builtin_amdgcn_sched_barrier(0);
            __builtin_amdgcn_s_setprio(1);
            #pragma unroll
            for (int kk = 0; kk < 2; ++kk)
                #pragma unroll
                for (int mm = 0; mm < 2; ++mm)
                    #pragma unroll
                    for (int n = 0; n < 4; ++n)
                        acc[2 * q + mm][n] = __builtin_amdgcn_mfma_f32_16x16x32_bf16(
                            af[mm][kk], bf[n][kk], acc[2 * q + mm][n], 0, 0, 0);
            __builtin_amdgcn_s_setprio(0);
            __builtin_amdgcn_sched_barrier(0);
            // counted wait ONCE per K-tile: 3 units (6 loads) stay in flight
            if (q == 3) asm volatile("s_waitcnt vmcnt(6)" ::: "memory");
            asm volatile("" ::: "memory");
            __builtin_amdgcn_s_barrier();
        }
    }

    // ---- epilogue: C/D 16x16 layout col=l16, row=quad*4+reg ----
    const int orow = bm0 + wm * 128 + quad * 4;
    #pragma unroll
    for (int n = 0; n < 4; ++n) {
        const int col = bn0 + wn * 64 + n * 16 + l16;
        const float bj = bias[col];
        #pragma unroll
        for (int m = 0; m < 8; ++m)
            #pragma unroll
            for (int r = 0; r < 4; ++r)
                out[(size_t)(orow + m * 16 + r) * DOUT + col] = acc[m][n][r] + bj;
    }
}

// ---------- host ----------
extern "C" void kernel_launch(void* const* d_in, const int* in_sizes, int n_in,
                              void* d_out, int out_size, void* d_ws, size_t ws_size,
                              hipStream_t stream) {
    const float* x  = (const float*)d_in[0];
    const float* bw = (const float*)d_in[1];
    const float* bb = (const float*)d_in[2];
    const float* Am = (const float*)d_in[3];
    const float* Bm = (const float*)d_in[4];
    const float* rw = (const float*)d_in[5];
    float* out = (float*)d_out;
    char* ws = (char*)d_ws;
    unsigned short* Xcat = (unsigned short*)(ws);                 // 8192*5120*2 = 83,886,080
    unsigned short* Wcat = (unsigned short*)(ws + 83886080);      // 4096*5120*2 = 41,943,040
    unsigned short* W1A  = (unsigned short*)(ws + 125829120);     // 64*4096*2   =    524,288
    float* Lg = (float*)(ws + 126353408);                         // 8192*16*4   =    524,288

    hipLaunchKernelGGL(prep_all_kernel, dim3(3072),   dim3(256), 0, stream,
                       x, rw, bw, Bm, Am, Xcat, Wcat, W1A, Lg);
    hipLaunchKernelGGL(proj_moe_kernel, dim3(512),    dim3(256), 0, stream,
                       Xcat, W1A, Lg, Xcat);
    hipLaunchKernelGGL(gemm_main_kernel, dim3(512),   dim3(512), 0, stream,
                       Xcat, Wcat, bb, out);
}

// Round 2
// 660.585 us; speedup vs baseline: 1.0894x; 1.0894x over previous
//
#include <hip/hip_runtime.h>
#include <cstdint>
#include <cstddef>

typedef short short8 __attribute__((ext_vector_type(8)));
typedef float f32x4 __attribute__((ext_vector_type(4)));
typedef float f32x16 __attribute__((ext_vector_type(16)));

#define DIN  4096
#define DOUT 4096
#define RANK 64
#define NEXP 16
#define NTOK 8192
#define KCAT 5120   // DIN + NEXP*RANK
#define NKT  (KCAT / 64)   // 80 K-tiles of 64
#define ROWB (KCAT * 2)    // 10240 bytes per row

// ---------- helpers ----------
__device__ __forceinline__ unsigned short f2bf(float f) {
    unsigned int u = __builtin_bit_cast(unsigned int, f);
    u = (u + 0x7FFFu + ((u >> 16) & 1u)) >> 16;   // RNE
    return (unsigned short)u;
}
__device__ __forceinline__ void async_cp16(const void* g, void* lds) {
    __builtin_amdgcn_global_load_lds(
        (const __attribute__((address_space(1))) void*)g,
        (__attribute__((address_space(3))) void*)lds, 16, 0, 0);
}

// ---------- kernel 1: all conversion + fp32 router logits ----------
__global__ void __launch_bounds__(256) prep_all_kernel(
        const float* __restrict__ x, const float* __restrict__ rw,
        const float* __restrict__ bw, const float* __restrict__ Bm,
        const float* __restrict__ Am,
        unsigned short* __restrict__ Xcat, unsigned short* __restrict__ Wcat,
        unsigned short* __restrict__ W1A, float* __restrict__ Lg) {
    __shared__ __align__(16) float xsl[8][532];
    __shared__ __align__(16) float red[8][16][16];
    const int tid = threadIdx.x;

    if (blockIdx.x < 1024) {
        const int t0 = blockIdx.x * 8;
        const int tt = tid >> 5, l32 = tid & 31;
        const int eg = tid >> 6, ts = (tid >> 4) & 3, cc = tid & 15;
        float part[2][4] = {};

        for (int w = 0; w < 8; ++w) {
            #pragma unroll
            for (int sub = 0; sub < 4; ++sub) {
                const int col = w * 512 + sub * 128 + l32 * 4;
                const float4 xv = *(const float4*)&x[(size_t)(t0 + tt) * DIN + col];
                unsigned short b0 = f2bf(xv.x), b1 = f2bf(xv.y),
                               b2 = f2bf(xv.z), b3 = f2bf(xv.w);
                uint2 pk = { (unsigned)b0 | ((unsigned)b1 << 16),
                             (unsigned)b2 | ((unsigned)b3 << 16) };
                *(uint2*)&Xcat[(size_t)(t0 + tt) * KCAT + col] = pk;
                *(float4*)&xsl[tt][sub * 128 + l32 * 4] = xv;
            }
            __syncthreads();
            #pragma unroll
            for (int j = 0; j < 8; ++j) {
                const int colb = w * 512 + (j * 16 + cc) * 4;
                const float4 r0 = *(const float4*)&rw[(size_t)(eg * 4 + 0) * DIN + colb];
                const float4 r1 = *(const float4*)&rw[(size_t)(eg * 4 + 1) * DIN + colb];
                const float4 r2 = *(const float4*)&rw[(size_t)(eg * 4 + 2) * DIN + colb];
                const float4 r3 = *(const float4*)&rw[(size_t)(eg * 4 + 3) * DIN + colb];
                #pragma unroll
                for (int t2 = 0; t2 < 2; ++t2) {
                    const int t = ts * 2 + t2;
                    const float4 xv = *(const float4*)&xsl[t][(j * 16 + cc) * 4];
                    part[t2][0] += xv.x * r0.x + xv.y * r0.y + xv.z * r0.z + xv.w * r0.w;
                    part[t2][1] += xv.x * r1.x + xv.y * r1.y + xv.z * r1.z + xv.w * r1.w;
                    part[t2][2] += xv.x * r2.x + xv.y * r2.y + xv.z * r2.z + xv.w * r2.w;
                    part[t2][3] += xv.x * r3.x + xv.y * r3.y + xv.z * r3.z + xv.w * r3.w;
                }
            }
            __syncthreads();
        }
        #pragma unroll
        for (int t2 = 0; t2 < 2; ++t2)
            #pragma unroll
            for (int e = 0; e < 4; ++e)
                red[ts * 2 + t2][eg * 4 + e][cc] = part[t2][e];
        __syncthreads();
        if (tid < 128) {
            const int t = tid >> 4, e = tid & 15;
            float s = 0.f;
            #pragma unroll
            for (int c = 0; c < 16; ++c) s += red[t][e][c];
            Lg[(size_t)(t0 + t) * NEXP + e] = s;
        }
    } else {
        const unsigned NG1 = (unsigned)DOUT * KCAT / 8u;       // 2,621,440
        const unsigned NGT = NG1 + 64u * DIN / 8u;             // + 32,768
        for (unsigned g = (blockIdx.x - 1024) * 256u + tid; g < NGT;
             g += 2048u * 256u) {
            const float* src;
            unsigned short* dst;
            if (g < NG1) {
                unsigned o  = g / 640u;
                unsigned c8 = (g - o * 640u) * 8u;
                dst = Wcat + (size_t)o * KCAT + c8;
                if (c8 < DIN) {
                    src = bw + (size_t)o * DIN + c8;
                } else {
                    unsigned cc2 = c8 - DIN;
                    unsigned e = cc2 >> 6, r = cc2 & 63u;
                    src = Bm + ((size_t)e * DOUT + o) * RANK + r;
                }
            } else {
                unsigned g2 = g - NG1;
                unsigned row = g2 >> 9;
                unsigned c8  = (g2 & 511u) * 8u;
                dst = W1A + (size_t)row * DIN + c8;
                src = Am + (size_t)row * DIN + c8;
            }
            float4 v0 = *(const float4*)(src);
            float4 v1 = *(const float4*)(src + 4);
            uint4 pk;
            pk.x = (unsigned)f2bf(v0.x) | ((unsigned)f2bf(v0.y) << 16);
            pk.y = (unsigned)f2bf(v0.z) | ((unsigned)f2bf(v0.w) << 16);
            pk.z = (unsigned)f2bf(v1.x) | ((unsigned)f2bf(v1.y) << 16);
            pk.w = (unsigned)f2bf(v1.z) | ((unsigned)f2bf(v1.w) << 16);
            *(uint4*)dst = pk;
        }
    }
}

// ---------- kernel 2: h = Xhi @ A^T (MFMA) + softmax/top2 -> H16 ----------
__global__ void __launch_bounds__(256) proj_moe_kernel(
        const unsigned short* __restrict__ Xcat,
        const unsigned short* __restrict__ W1A,
        const float* __restrict__ Lg, unsigned short* __restrict__ XcatW) {
    __shared__ __align__(16) unsigned short Xs[16 * 128];   // 4 KB
    __shared__ __align__(16) unsigned short Ws[64 * 128];   // 16 KB
    __shared__ __align__(16) float cw[16][16];
    __shared__ __align__(16) float hbuf[16][68];
    const int tid = threadIdx.x;
    const int wave = tid >> 6, lane = tid & 63;
    const int quad = lane >> 4, l16 = lane & 15;
    const int t0 = blockIdx.x * 16;

    const int rX = tid >> 4, cXs = tid & 15;
    const int cX = (cXs & 8) | ((cXs ^ rX) & 7);

    if (tid < 16) {
        float l[16];
        #pragma unroll
        for (int e = 0; e < 16; ++e) l[e] = Lg[(size_t)(t0 + tid) * NEXP + e];
        int i1 = 0; float b1v = l[0];
        #pragma unroll
        for (int e = 1; e < 16; ++e) if (l[e] > b1v) { b1v = l[e]; i1 = e; }
        int i2 = -1; float b2v = -1e30f;
        #pragma unroll
        for (int e = 0; e < 16; ++e) if (e != i1 && l[e] > b2v) { b2v = l[e]; i2 = e; }
        float S = 0.f;
        #pragma unroll
        for (int e = 0; e < 16; ++e) S += expf(l[e] - b1v);
        const float p1 = 1.0f / S;
        const float p2 = expf(b2v - b1v) / S;
        const float d = p1 + p2 + 1e-6f;
        const float c1 = 0.5f * p1 / d;
        const float c2 = 0.5f * p2 / d;
        #pragma unroll
        for (int e = 0; e < 16; ++e)
            cw[tid][e] = (e == i1) ? c1 : (e == i2) ? c2 : 0.0f;
    }

    f32x4 acc = {};
    for (int kt = 0; kt < DIN / 128; ++kt) {
        const int k0 = kt * 128;
        async_cp16(Xcat + (size_t)(t0 + rX) * KCAT + k0 + cX * 8,
                   (char*)Xs + wave * 1024);
        #pragma unroll
        for (int i = 0; i < 4; ++i) {
            const int s = i * 256 + tid;
            const int rW = s >> 4, cWs = s & 15;
            const int cWc = (cWs & 8) | ((cWs ^ rW) & 7);
            async_cp16(W1A + (size_t)rW * DIN + k0 + cWc * 8,
                       (char*)Ws + i * 4096 + wave * 1024);
        }
        __syncthreads();
        #pragma unroll
        for (int kk = 0; kk < 4; ++kk) {
            const int c = kk * 4 + quad;
            const int sa = ((c & 8) | ((c ^ l16) & 7)) << 3;
            const int rb = wave * 16 + l16;
            const int sb = ((c & 8) | ((c ^ rb) & 7)) << 3;
            short8 am = *(const short8*)&Xs[l16 * 128 + sa];
            short8 bn = *(const short8*)&Ws[rb * 128 + sb];
            acc = __builtin_amdgcn_mfma_f32_16x16x32_bf16(am, bn, acc, 0, 0, 0);
        }
        __syncthreads();
    }
    #pragma unroll
    for (int r = 0; r < 4; ++r)
        hbuf[quad * 4 + r][wave * 16 + l16] = acc[r];
    __syncthreads();
    const int t = tid >> 4, e = tid & 15;
    const float c = cw[t][e];
    unsigned short* dst = XcatW + (size_t)(t0 + t) * KCAT + DIN + e * 64;
    #pragma unroll
    for (int r8 = 0; r8 < 8; ++r8) {
        unsigned short o16[8];
        #pragma unroll
        for (int k = 0; k < 8; ++k)
            o16[k] = f2bf(c * hbuf[t][r8 * 8 + k]);
        uint4 pk;
        pk.x = (unsigned)o16[0] | ((unsigned)o16[1] << 16);
        pk.y = (unsigned)o16[2] | ((unsigned)o16[3] << 16);
        pk.z = (unsigned)o16[4] | ((unsigned)o16[5] << 16);
        pk.w = (unsigned)o16[6] | ((unsigned)o16[7] << 16);
        *(uint4*)(dst + r8 * 8) = pk;
    }
}

// ---------- kernel 3: out = Xcat @ Wcat^T + bias ----------
// 256x256 tile, BK=64, 8 waves (2M x 4N), 32x32x16 MFMA, 4-phase schedule,
// counted vmcnt(6), register-level fragment prefetch into the MFMA window,
// linear [256][64] LDS rows with in-row slot-XOR swizzle (slot = k ^ (row&7)).
__global__ void __launch_bounds__(512, 2) gemm_main_kernel(
        const unsigned short* __restrict__ Xcat,
        const unsigned short* __restrict__ Wcat,
        const float* __restrict__ bias, float* __restrict__ out) {
    __shared__ __align__(16) unsigned short As[2][256 * 64];   // 2 x 32 KB
    __shared__ __align__(16) unsigned short Bs[2][256 * 64];   // 2 x 32 KB

    const int tid  = threadIdx.x;
    const int wave = tid >> 6, lane = tid & 63;
    const int r5   = lane & 31, hi = lane >> 5, xb = r5 & 7;
    const int wm   = wave >> 2, wn = wave & 3;

    // T1: XCD swizzle (512 blocks, 512 % 8 == 0 -> bijective remap)
    const int bid = blockIdx.x;
    const int swz = (bid & 7) * 64 + (bid >> 3);
    const int bm0 = (swz & 31) * 256;   // 32 M-tiles
    const int bn0 = (swz >> 5) * 256;   // 16 N-tiles

    // ---- staging: pre-swizzled global source, linear LDS dest ----
    // LDS row r stored at byte r*128; 16B slot s of row r holds k-chunk s^(r&7).
    const int urr = tid >> 3;                    // 0..63 row within a 64-row group
    const int cks = (tid & 7) ^ (urr & 7);       // pre-swizzled k-chunk
    const unsigned voffG = (unsigned)(urr * KCAT + cks * 8) * 2u;   // bytes

    const char* gA = (const char*)Xcat + (size_t)bm0 * ROWB + voffG;
    const char* gB = (const char*)Wcat + (size_t)bn0 * ROWB + voffG;
    char* const ldsA  = (char*)&As[0][0];
    char* const ldsB  = (char*)&Bs[0][0];
    char* const ldswA = ldsA + wave * 1024;
    char* const ldswB = ldsB + wave * 1024;

    // A unit h: rows {h*64..h*64+63} -> byte h*8192, {128+h*64..} -> 16384+h*8192
    // B unit u: rows {u*128..+63} -> byte u*16384, {u*128+64..} -> u*16384+8192
#define STAGE_A(H, TT, BOFF2) { \
    async_cp16(gA + (size_t)((H) * 64) * ROWB + (size_t)(TT) * 128, \
               ldswA + (BOFF2) + (H) * 8192); \
    async_cp16(gA + (size_t)((H) * 64 + 128) * ROWB + (size_t)(TT) * 128, \
               ldswA + (BOFF2) + (H) * 8192 + 16384); }
#define STAGE_B(U, TT, BOFF2) { \
    async_cp16(gB + (size_t)((U) * 128) * ROWB + (size_t)(TT) * 128, \
               ldswB + (BOFF2) + (U) * 16384); \
    async_cp16(gB + (size_t)((U) * 128 + 64) * ROWB + (size_t)(TT) * 128, \
               ldswB + (BOFF2) + (U) * 16384 + 8192); }

    // ---- LDS read vaddrs: byte = row*128 + ((2kk+hi)^(row&7))*16 ----
    int vA[4], vB[4];
    #pragma unroll
    for (int kk = 0; kk < 4; ++kk) {
        const int vb = r5 * 128 + (((2 * kk + hi) ^ xb) * 16);
        vA[kk] = vb + wm * 8192;   // wave M-half base (rows wm*64 / 128+wm*64)
        vB[kk] = vb + wn * 8192;   // wave N base (rows wn*64)
    }

    f32x16 acc00 = {}, acc01 = {}, acc10 = {}, acc11 = {};
    f32x16 acc20 = {}, acc21 = {}, acc30 = {}, acc31 = {};
    short8 bf0[4], bf1[4], fE[4], fO[4];

    // af(q) row imm: (q>>1)*16384 + (q&1)*4096
#define PREF_AF(DST, Q, BOFF2) { \
    _Pragma("unroll") \
    for (int kk = 0; kk < 4; ++kk) \
        DST[kk] = *(const short8*)(ldsA + (BOFF2) + vA[kk] + \
                                   ((Q) >> 1) * 16384 + ((Q) & 1) * 4096); }
#define MFMA8(AF, A0, A1) { \
    __builtin_amdgcn_s_setprio(1); \
    _Pragma("unroll") \
    for (int kk = 0; kk < 4; ++kk) { \
        A0 = __builtin_amdgcn_mfma_f32_32x32x16_bf16(AF[kk], bf0[kk], A0, 0, 0, 0); \
        A1 = __builtin_amdgcn_mfma_f32_32x32x16_bf16(AF[kk], bf1[kk], A1, 0, 0, 0); \
    } \
    __builtin_amdgcn_s_setprio(0); }
#define CLOB asm volatile("" ::: "memory")
#define BAR  __builtin_amdgcn_s_barrier()
#define LGKM0 { asm volatile("s_waitcnt lgkmcnt(0)" ::: "memory"); \
                __builtin_amdgcn_sched_barrier(0); }
#define SBAR __builtin_amdgcn_sched_barrier(0)

    // ---- prologue: tile0 fully + tile1 {B0,B1,Ah0}; wait 8 of 14 ----
    STAGE_B(0, 0, 0);     STAGE_B(1, 0, 0);
    STAGE_A(0, 0, 0);     STAGE_A(1, 0, 0);
    STAGE_B(0, 1, 32768); STAGE_B(1, 1, 32768);
    STAGE_A(0, 1, 32768);
    asm volatile("s_waitcnt vmcnt(6)" ::: "memory");
    CLOB; BAR; CLOB;

    #pragma unroll 2
    for (int t = 0; t < NKT; ++t) {
        const int boff = (t & 1) * 32768;
        const int ob   = boff ^ 32768;
        const int ts1  = (t + 1 < NKT) ? t + 1 : t;
        const int ts2  = (t + 2 < NKT) ? t + 2 : t;

        // ---- q0: own reads (bf + af0), stage A-h1(t+1) -> other buffer ----
        #pragma unroll
        for (int kk = 0; kk < 4; ++kk) {
            bf0[kk] = *(const short8*)(ldsB + boff + vB[kk]);
            bf1[kk] = *(const short8*)(ldsB + boff + vB[kk] + 4096);
            fE[kk]  = *(const short8*)(ldsA + boff + vA[kk]);
        }
        STAGE_A(1, ts1, ob);
        CLOB; BAR;
        LGKM0;
        PREF_AF(fO, 1, boff); SBAR;
        MFMA8(fE, acc00, acc01);
        SBAR; CLOB; BAR;

        // ---- q1: stage B0(t+2) -> cur buffer (bf dead), use fO, pref af2 ----
        STAGE_B(0, ts2, boff);
        CLOB; BAR;
        LGKM0;
        PREF_AF(fE, 2, boff); SBAR;
        MFMA8(fO, acc10, acc11);
        SBAR; CLOB; BAR;

        // ---- q2: stage B1(t+2) -> cur buffer, use fE, pref af3 ----
        STAGE_B(1, ts2, boff);
        CLOB; BAR;
        LGKM0;
        PREF_AF(fO, 3, boff); SBAR;
        MFMA8(fE, acc20, acc21);
        SBAR; CLOB; BAR;

        // ---- q3: stage A-h0(t+2) -> cur buffer, use fO, counted vmcnt ----
        STAGE_A(0, ts2, boff);
        CLOB; BAR;
        LGKM0;
        MFMA8(fO, acc30, acc31);
        SBAR;
        asm volatile("s_waitcnt vmcnt(6)" ::: "memory");
        CLOB; BAR;
    }

    // ---- epilogue: C/D 32x32 layout col=lane&31, row=(r&3)+8*(r>>2)+4*hi ----
#define EPI(Q, A0, A1) { \
    const int rb = bm0 + ((Q) >> 1) * 128 + wm * 64 + ((Q) & 1) * 32 + 4 * hi; \
    { const int col = bn0 + wn * 64 + r5; const float bj = bias[col]; \
      _Pragma("unroll") for (int r = 0; r < 16; ++r) { \
        const int row = rb + (r & 3) + 8 * (r >> 2); \
        out[(size_t)row * DOUT + col] = A0[r] + bj; } } \
    { const int col = bn0 + wn * 64 + 32 + r5; const float bj = bias[col]; \
      _Pragma("unroll") for (int r = 0; r < 16; ++r) { \
        const int row = rb + (r & 3) + 8 * (r >> 2); \
        out[(size_t)row * DOUT + col] = A1[r] + bj; } } }
    EPI(0, acc00, acc01)
    EPI(1, acc10, acc11)
    EPI(2, acc20, acc21)
    EPI(3, acc30, acc31)
#undef STAGE_A
#undef STAGE_B
#undef PREF_AF
#undef MFMA8
#undef CLOB
#undef BAR
#undef LGKM0
#undef SBAR
#undef EPI
}

// ---------- host ----------
extern "C" void kernel_launch(void* const* d_in, const int* in_sizes, int n_in,
                              void* d_out, int out_size, void* d_ws, size_t ws_size,
                              hipStream_t stream) {
    const float* x  = (const float*)d_in[0];
    const float* bw = (const float*)d_in[1];
    const float* bb = (const float*)d_in[2];
    const float* Am = (const float*)d_in[3];
    const float* Bm = (const float*)d_in[4];
    const float* rw = (const float*)d_in[5];
    float* out = (float*)d_out;
    char* ws = (char*)d_ws;
    unsigned short* Xcat = (unsigned short*)(ws);                 // 8192*5120*2 = 83,886,080
    unsigned short* Wcat = (unsigned short*)(ws + 83886080);      // 4096*5120*2 = 41,943,040
    unsigned short* W1A  = (unsigned short*)(ws + 125829120);     // 64*4096*2   =    524,288
    float* Lg = (float*)(ws + 126353408);                         // 8192*16*4   =    524,288

    hipLaunchKernelGGL(prep_all_kernel, dim3(3072),   dim3(256), 0, stream,
                       x, rw, bw, Bm, Am, Xcat, Wcat, W1A, Lg);
    hipLaunchKernelGGL(proj_moe_kernel, dim3(512),    dim3(256), 0, stream,
                       Xcat, W1A, Lg, Xcat);
    hipLaunchKernelGGL(gemm_main_kernel, dim3(512),   dim3(512), 0, stream,
                       Xcat, Wcat, bb, out);
}